// Round 10
// baseline (62.487 us; speedup 1.0000x reference)
//
#include <hip/hip_runtime.h>
#include <math.h>

typedef float f32x4 __attribute__((ext_vector_type(4)));

// Problem constants (fixed by the reference setup)
constexpr int Bb = 32;
constexpr int Ss = 2048;
constexpr int Hh = 1024;
constexpr int SC = 128;                // s-rows per block in fused kernel
constexpr int CPB = Ss / SC;           // 16 chunks per batch
constexpr int NBLK = Bb * CPB;         // 512 blocks (2 blocks/CU, one round)

// ---------------- Kernel A: h = hidden @ W_in^T (R3/R5 version) ----------------
// Block = (output index i, group of 4 batches). i = blk & 1023 so the 8 blocks
// sharing W row i are 1024 apart -> same XCD -> W row fetched from HBM once.
__global__ __launch_bounds__(256) void gemv_h_kernel(const float* __restrict__ hidden,
                                                     const float* __restrict__ W,
                                                     float* __restrict__ h)
{
    int tid  = threadIdx.x;
    int wave = tid >> 6;
    int lane = tid & 63;
    int i  = blockIdx.x & (Hh - 1);    // 0..1023
    int bg = blockIdx.x >> 10;         // 0..7
    int b  = bg * 4 + wave;            // 0..31
    const f32x4* wr = reinterpret_cast<const f32x4*>(W + (size_t)i * Hh);
    const f32x4* hd = reinterpret_cast<const f32x4*>(hidden + (size_t)b * Hh);
    float d = 0.f;
#pragma unroll
    for (int k = 0; k < 4; ++k) {
        f32x4 wv = wr[lane + 64 * k];
        f32x4 hv = hd[lane + 64 * k];
        d += wv[0] * hv[0] + wv[1] * hv[1] + wv[2] * hv[2] + wv[3] * hv[3];
    }
#pragma unroll
    for (int off = 32; off > 0; off >>= 1) d += __shfl_xor(d, off, 64);
    if (lane == 0) h[(size_t)b * Hh + i] = d;
}

// ---------------- Kernel B: fused scores + online softmax + partial context ----
// R5-exact structure (best measured: 59.9 us total) with ONE change: enc loads
// are NONTEMPORAL (nt) — enc is 256 MiB read exactly once; bypassing L2
// allocation avoids thrashing the 32 MiB L2 with never-reused lines.
// Block = (batch b, chunk of SC=128 rows). 4 waves, 32 rows/wave = 8 quads,
// ping-pong register prefetch (quad q+1 issued before compute of quad q).
__global__ __launch_bounds__(256) void attn_partial_kernel(const float* __restrict__ enc,
                                                           const float* __restrict__ h,
                                                           float* __restrict__ scores,
                                                           float* __restrict__ pm,
                                                           float* __restrict__ pl,
                                                           float* __restrict__ pctx)
{
    int blk   = blockIdx.x;           // 0..NBLK-1
    int b     = blk >> 4;             // / CPB (CPB = 16)
    int chunk = blk & (CPB - 1);
    int s0    = chunk * SC;
    int tid   = threadIdx.x;
    int wave  = tid >> 6;
    int lane  = tid & 63;

    // h fragment for this lane (elements 4*lane + 256*k)
    f32x4 hf[4];
    const f32x4* h4 = reinterpret_cast<const f32x4*>(h + (size_t)b * Hh);
#pragma unroll
    for (int k = 0; k < 4; ++k) hf[k] = h4[lane + 64 * k];

    float m = -INFINITY;
    float l = 0.f;
    f32x4 ctx[4];
#pragma unroll
    for (int k = 0; k < 4; ++k) ctx[k] = (f32x4)(0.f);

    const f32x4* ebase = reinterpret_cast<const f32x4*>(enc + ((size_t)b * Ss + s0 + wave * 32) * Hh);

#define LOADQ(EV, Q)                                                        \
    {                                                                       \
        _Pragma("unroll")                                                   \
        for (int r = 0; r < 4; ++r) {                                       \
            const f32x4* e4 = ebase + (size_t)((Q) * 4 + r) * (Hh / 4);     \
            _Pragma("unroll")                                               \
            for (int k = 0; k < 4; ++k)                                     \
                EV[r][k] = __builtin_nontemporal_load(e4 + lane + 64 * k);  \
        }                                                                   \
    }

#define COMPQ(EV, Q)                                                        \
    {                                                                       \
        float d[4];                                                         \
        _Pragma("unroll")                                                   \
        for (int r = 0; r < 4; ++r) {                                       \
            d[r] = 0.f;                                                     \
            _Pragma("unroll")                                               \
            for (int k = 0; k < 4; ++k) {                                   \
                _Pragma("unroll")                                           \
                for (int c = 0; c < 4; ++c) d[r] += EV[r][k][c] * hf[k][c]; \
            }                                                               \
        }                                                                   \
        _Pragma("unroll")                                                   \
        for (int off = 32; off > 0; off >>= 1) {                            \
            _Pragma("unroll")                                               \
            for (int r = 0; r < 4; ++r) d[r] += __shfl_xor(d[r], off, 64);  \
        }                                                                   \
        if (lane == 0) {                                                    \
            *reinterpret_cast<float4*>(scores + (size_t)b * Ss + s0 +       \
                                       wave * 32 + 4 * (Q)) =               \
                make_float4(d[0], d[1], d[2], d[3]);                        \
        }                                                                   \
        float mn = fmaxf(fmaxf(fmaxf(d[0], d[1]), fmaxf(d[2], d[3])), m);   \
        if (mn > m) {                                                       \
            float c = __expf(m - mn);                                       \
            l *= c;                                                         \
            _Pragma("unroll")                                               \
            for (int k = 0; k < 4; ++k) ctx[k] *= c;                        \
            m = mn;                                                         \
        }                                                                   \
        float p[4];                                                         \
        _Pragma("unroll")                                                   \
        for (int r = 0; r < 4; ++r) p[r] = __expf(d[r] - m);                \
        l += (p[0] + p[1]) + (p[2] + p[3]);                                 \
        _Pragma("unroll")                                                   \
        for (int k = 0; k < 4; ++k) {                                       \
            _Pragma("unroll")                                               \
            for (int r = 0; r < 4; ++r) ctx[k] += p[r] * EV[r][k];          \
        }                                                                   \
    }

    f32x4 evA[4][4], evB[4][4];
    LOADQ(evA, 0);
#pragma unroll 1
    for (int qq = 0; qq < 3; ++qq) {
        LOADQ(evB, 2 * qq + 1);
        COMPQ(evA, 2 * qq);
        LOADQ(evA, 2 * qq + 2);
        COMPQ(evB, 2 * qq + 1);
    }
    LOADQ(evB, 7);
    COMPQ(evA, 6);
    COMPQ(evB, 7);
#undef LOADQ
#undef COMPQ

    // intra-block combine across 4 waves via LDS
    __shared__ f32x4 lds_ctx[4][Hh / 4];   // 16 KiB
    __shared__ float lds_m[4], lds_l[4];
#pragma unroll
    for (int k = 0; k < 4; ++k) lds_ctx[wave][64 * k + lane] = ctx[k];
    if (lane == 0) { lds_m[wave] = m; lds_l[wave] = l; }
    __syncthreads();

    float M = fmaxf(fmaxf(lds_m[0], lds_m[1]), fmaxf(lds_m[2], lds_m[3]));
    float L = 0.f;
    f32x4 acc = (f32x4)(0.f);
#pragma unroll
    for (int w = 0; w < 4; ++w) {
        float c = __expf(lds_m[w] - M);
        L += c * lds_l[w];
        acc += c * lds_ctx[w][tid];
    }
    reinterpret_cast<f32x4*>(pctx + (size_t)blk * Hh)[tid] = acc;
    if (tid == 0) { pm[blk] = M; pl[blk] = L; }
}

// ---------------- Kernel CD: combine partials -> context, scores -> attn_w ----
// Blocks [0,128): combine (b = blk>>2, 256-wide H slice). Blocks [128,384):
// finish attn_w; every thread recomputes (M,L) from pm/pl (L2 broadcast, cheap)
// so there is no cross-block dependency.
__global__ __launch_bounds__(256) void combine_finish_kernel(const float* __restrict__ pm,
                                                             const float* __restrict__ pl,
                                                             const float* __restrict__ pctx,
                                                             const float* __restrict__ scores,
                                                             float* __restrict__ out_ctx,
                                                             float* __restrict__ attn_out)
{
    int blk = blockIdx.x;
    int tid = threadIdx.x;
    if (blk < 128) {
        int b = blk >> 2;
        int col = (blk & 3) * 256 + tid;
        const float* mrow = pm + (size_t)b * CPB;
        const float* lrow = pl + (size_t)b * CPB;
        float M = -INFINITY;
#pragma unroll
        for (int c = 0; c < CPB; ++c) M = fmaxf(M, mrow[c]);
        float e[CPB];
        float L = 0.f;
#pragma unroll
        for (int c = 0; c < CPB; ++c) {
            e[c] = __expf(mrow[c] - M);
            L += e[c] * lrow[c];
        }
        float acc = 0.f;
#pragma unroll 4
        for (int c = 0; c < CPB; ++c)
            acc += e[c] * pctx[((size_t)b * CPB + c) * Hh + col];
        out_ctx[(size_t)b * Hh + col] = acc / L;
    } else {
        int idx = (blk - 128) * 256 + tid;   // 0..B*S-1
        int b = idx >> 11;                   // / S
        const float* mrow = pm + (size_t)b * CPB;
        const float* lrow = pl + (size_t)b * CPB;
        float M = -INFINITY;
#pragma unroll
        for (int c = 0; c < CPB; ++c) M = fmaxf(M, mrow[c]);
        float L = 0.f;
#pragma unroll
        for (int c = 0; c < CPB; ++c) L += __expf(mrow[c] - M) * lrow[c];
        attn_out[idx] = __expf(scores[idx] - M) / L;
    }
}

extern "C" void kernel_launch(void* const* d_in, const int* in_sizes, int n_in,
                              void* d_out, int out_size, void* d_ws, size_t ws_size,
                              hipStream_t stream) {
    const float* hidden = (const float*)d_in[0];   // [B,H]
    const float* enc    = (const float*)d_in[1];   // [B,S,H]
    const float* W_in   = (const float*)d_in[2];   // [H,H]

    float* out_ctx  = (float*)d_out;               // [B,H]   context first
    float* out_attn = (float*)d_out + Bb * Hh;     // [B,S]

    float* ws     = (float*)d_ws;
    float* h      = ws;                            // B*H      = 32768
    float* scores = ws + 32768;                    // B*S      = 65536
    float* pm     = ws + 98304;                    // NBLK     = 512
    float* pl     = ws + 98816;                    // NBLK     = 512
    float* pctx   = ws + 99328;                    // NBLK*H   = 524288
    (void)in_sizes; (void)n_in; (void)out_size; (void)ws_size;

    // A: h = hidden @ W_in^T   (XCD-local W-row reuse)
    gemv_h_kernel<<<Hh * (Bb / 4), 256, 0, stream>>>(hidden, W_in, h);
    // B: fused scores + online softmax + partial context (R5 structure +
    //    nontemporal enc loads)
    attn_partial_kernel<<<NBLK, 256, 0, stream>>>(enc, h, scores, pm, pl, pctx);
    // CD: combine -> context, and scores -> attn_w (no cross-block dependency)
    combine_finish_kernel<<<128 + (Bb * Ss) / 256, 256, 0, stream>>>(pm, pl, pctx, scores,
                                                                     out_ctx, out_attn);
}